// Round 5
// baseline (265.815 us; speedup 1.0000x reference)
//
#include <hip/hip_runtime.h>
#include <hip/hip_fp16.h>

// ---------------- types ----------------
typedef _Float16 half8 __attribute__((ext_vector_type(8)));
typedef _Float16 half4v __attribute__((ext_vector_type(4)));
typedef float f32x4 __attribute__((ext_vector_type(4)));

#define GAS1(p) ((const __attribute__((address_space(1))) void*)(p))
#define LAS3(p) ((__attribute__((address_space(3))) void*)(p))

// Problem constants: B=8, N=1024, C=1024, H=16, D_HEAD=64, BH=128, M=8192
#define SCALE 0.125f
#define LOG2E 1.44269504088896340736f
#define RESCALE_THR 8.0f

// ---------------- f32 -> f16 conversion (vectorized) ----------------
__global__ void cvt_f32_f16(const float* __restrict__ in, _Float16* __restrict__ out) {
  int i = blockIdx.x * 256 + threadIdx.x;
  float4 f = reinterpret_cast<const float4*>(in)[i];
  half4v h;
  h[0] = (_Float16)f.x; h[1] = (_Float16)f.y;
  h[2] = (_Float16)f.z; h[3] = (_Float16)f.w;
  reinterpret_cast<half4v*>(out)[i] = h;
}

// ---------------- 128x128 GEMM, BK=64, C = A @ Bw^T (+bias) ----------------
// A: [M][K] row-major f16.  Bw: [N][K] row-major f16 (i.e. B-transposed input).
// EPI=0: Cf[m*Ndim+n] = acc + bias[n]  (fp32 out)
// EPI=1: qkv scatter: n -> (t,h,d); q scaled by SCALE; v written transposed.
// __launch_bounds__(256,3): 3 blocks/CU = m97's measured occupancy; the
// barrier-drain stall is hidden by cross-block overlap (2 blocks/CU halved it).
template<int EPI>
__launch_bounds__(256, 3)
__global__ void gemm128(const _Float16* __restrict__ A, const _Float16* __restrict__ Bw,
                        const float* __restrict__ bias,
                        float* __restrict__ Cf,
                        _Float16* __restrict__ qo, _Float16* __restrict__ ko,
                        _Float16* __restrict__ vto,
                        int Kdim, int Ndim) {
  __shared__ alignas(128) _Float16 As[128 * 64];
  __shared__ alignas(128) _Float16 Bs[128 * 64];
  const int tid = threadIdx.x;
  const int w = tid >> 6, lane = tid & 63, lo = lane & 15, hi = lane >> 4;
  const int wr = w >> 1, wc = w & 1;
  const int tm0 = blockIdx.x * 128;
  const int tn0 = blockIdx.y * 128;

  f32x4 acc[4][4] = {};

  for (int k0 = 0; k0 < Kdim; k0 += 64) {
    __syncthreads();  // previous compute done before overwrite
#pragma unroll
    for (int r = 0; r < 4; ++r) {
      // dest linear, source inverse-swizzled (rule 21).
      int o = r * 4096 + w * 1024 + lane * 16;
      int row = o >> 7;
      int kk = ((o & 127) ^ ((row & 7) << 4)) >> 1;
      __builtin_amdgcn_global_load_lds(GAS1(A + (size_t)(tm0 + row) * Kdim + k0 + kk),
                                       LAS3((char*)As + r * 4096 + w * 1024), 16, 0, 0);
      __builtin_amdgcn_global_load_lds(GAS1(Bw + (size_t)(tn0 + row) * Kdim + k0 + kk),
                                       LAS3((char*)Bs + r * 4096 + w * 1024), 16, 0, 0);
    }
    __syncthreads();  // compiler drains vmcnt before barrier
#pragma unroll
    for (int s = 0; s < 2; ++s) {
      half8 af[4], bf[4];
#pragma unroll
      for (int i = 0; i < 4; ++i) {
        int arow = wr * 64 + i * 16 + lo;
        int abyte = (arow << 7) + ((hi * 16 + s * 64) ^ ((arow & 7) << 4));
        af[i] = *reinterpret_cast<const half8*>((const char*)As + abyte);
        int brow = wc * 64 + i * 16 + lo;
        int bbyte = (brow << 7) + ((hi * 16 + s * 64) ^ ((brow & 7) << 4));
        bf[i] = *reinterpret_cast<const half8*>((const char*)Bs + bbyte);
      }
#pragma unroll
      for (int i = 0; i < 4; ++i)
#pragma unroll
        for (int j = 0; j < 4; ++j)
          acc[i][j] = __builtin_amdgcn_mfma_f32_16x16x32_f16(af[i], bf[j], acc[i][j], 0, 0, 0);
    }
  }

  // Epilogue.  D layout: row = hi*4 + reg, col = lo (m89-verified).
  if (EPI == 0) {
#pragma unroll
    for (int i = 0; i < 4; ++i) {
      const int m0 = tm0 + wr * 64 + i * 16 + hi * 4;
#pragma unroll
      for (int j = 0; j < 4; ++j) {
        const int n = tn0 + wc * 64 + j * 16 + lo;
        const float bj = bias[n];
#pragma unroll
        for (int r = 0; r < 4; ++r)
          Cf[(size_t)(m0 + r) * Ndim + n] = acc[i][j][r] + bj;
      }
    }
  } else {
    const int t = tn0 >> 10;  // block-uniform: 1024 % 128 == 0
#pragma unroll
    for (int i = 0; i < 4; ++i) {
      const int m0 = tm0 + wr * 64 + i * 16 + hi * 4;
      const int b = m0 >> 10;
      const int nr = m0 & 1023;
#pragma unroll
      for (int j = 0; j < 4; ++j) {
        const int n = tn0 + wc * 64 + j * 16 + lo;
        const float bj = bias[n];
        const int h = (n >> 6) & 15;
        const int d = n & 63;
        const size_t hb = ((size_t)(b * 16 + h)) << 16;  // *65536
        if (t == 0) {
#pragma unroll
          for (int r = 0; r < 4; ++r)
            qo[hb + (size_t)(nr + r) * 64 + d] = (_Float16)((acc[i][j][r] + bj) * SCALE);
        } else if (t == 1) {
#pragma unroll
          for (int r = 0; r < 4; ++r)
            ko[hb + (size_t)(nr + r) * 64 + d] = (_Float16)(acc[i][j][r] + bj);
        } else {
          half4v v4;
#pragma unroll
          for (int r = 0; r < 4; ++r) v4[r] = (_Float16)(acc[i][j][r] + bj);
          // V transposed: vt[bh][d][n]; nr % 4 == 0 -> 8B aligned
          *reinterpret_cast<half4v*>(vto + hb + (size_t)d * 1024 + nr) = v4;
        }
      }
    }
  }
}

// ---------------- flash attention v5 (swapped-operand) ----------------
// q,k: [BH][1024][64] f16 (q pre-scaled).  vt: [BH][64][1024] f16.
// z out: [B][1024][C] f16.  Grid dim3(8,128).
// vs v4: per-rg P buffers (both P writes before first PV read -> longer
// lgkm distance), V-fragments hoisted across rg (8 fewer ds_read_b128/tile).
// LDS 48 KB -> 3 blocks/CU.
__launch_bounds__(256, 3)
__global__ void attn_kernel(const _Float16* __restrict__ q, const _Float16* __restrict__ kb,
                            const _Float16* __restrict__ vt, _Float16* __restrict__ z) {
  __shared__ alignas(128) _Float16 Ks[2][64 * 64];     // 16 KB
  __shared__ alignas(128) _Float16 Vs[2][64 * 64];     // 16 KB  (rows = d, cols = n)
  __shared__ alignas(128) _Float16 P[4][2][16 * 64];   // 16 KB, per-wave per-rg
  const int tid = threadIdx.x;
  const int w = tid >> 6, lane = tid & 63, lo = lane & 15, hi = lane >> 4;
  const int bh = blockIdx.y;
  const int qr0 = blockIdx.x * 128 + w * 32;
  const size_t base = (size_t)bh << 16;  // *65536

  // stage one 64x64 K-tile and Vt-tile into LDS buffer `buf` (rule 21:
  // linear dest, inverse-swizzled source; reads below apply the swizzle).
  auto stage = [&](int buf, int kt) {
#pragma unroll
    for (int p = 0; p < 2; ++p) {
      int o = p * 4096 + w * 1024 + lane * 16;
      int row = o >> 7;
      int kk = ((o & 127) ^ ((row & 7) << 4)) >> 1;
      __builtin_amdgcn_global_load_lds(GAS1(kb + base + (size_t)(kt + row) * 64 + kk),
                                       LAS3((char*)&Ks[buf][0] + p * 4096 + w * 1024), 16, 0, 0);
      __builtin_amdgcn_global_load_lds(GAS1(vt + base + (size_t)row * 1024 + kt + kk),
                                       LAS3((char*)&Vs[buf][0] + p * 4096 + w * 1024), 16, 0, 0);
    }
  };

  stage(0, 0);

  half8 qf[2][2];  // B-fragment: lane lo = q-row qr0+rg*16+lo, k-slice s*32+hi*8
#pragma unroll
  for (int rg = 0; rg < 2; ++rg)
#pragma unroll
    for (int s = 0; s < 2; ++s)
      qf[rg][s] = *reinterpret_cast<const half8*>(
          q + base + (size_t)(qr0 + rg * 16 + lo) * 64 + s * 32 + hi * 8);

  f32x4 zacc[2][4] = {};        // Z^T: zacc[rg][v][u] = Z[q=lo][d=16v+4hi+u]
  float m_s[2] = {-1e30f, -1e30f};
  float l_s[2] = {0.f, 0.f};

  __syncthreads();

  int buf = 0;
  for (int kt = 0; kt < 1024; kt += 64) {
    if (kt + 64 < 1024) stage(buf ^ 1, kt + 64);
    const char* Kb = (const char*)&Ks[buf][0];
    const char* Vb = (const char*)&Vs[buf][0];

    // ---- S^T = mfma(K, Q): sacc[rg][c][u] = S[q=lo][k=16c+4hi+u] ----
    f32x4 sacc[2][4];
#pragma unroll
    for (int rg = 0; rg < 2; ++rg)
#pragma unroll
      for (int c = 0; c < 4; ++c) sacc[rg][c] = f32x4{0.f, 0.f, 0.f, 0.f};
#pragma unroll
    for (int c = 0; c < 4; ++c) {
      const int row = c * 16 + lo;
      half8 bK0 = *reinterpret_cast<const half8*>(
          Kb + (row << 7) + ((hi * 16) ^ ((row & 7) << 4)));
      half8 bK1 = *reinterpret_cast<const half8*>(
          Kb + (row << 7) + ((64 + hi * 16) ^ ((row & 7) << 4)));
      __builtin_amdgcn_s_setprio(1);
#pragma unroll
      for (int rg = 0; rg < 2; ++rg) {
        sacc[rg][c] = __builtin_amdgcn_mfma_f32_16x16x32_f16(bK0, qf[rg][0], sacc[rg][c], 0, 0, 0);
        sacc[rg][c] = __builtin_amdgcn_mfma_f32_16x16x32_f16(bK1, qf[rg][1], sacc[rg][c], 0, 0, 0);
      }
      __builtin_amdgcn_s_setprio(0);
    }

    // ---- softmax + P writes for BOTH rg before any PV read ----
#pragma unroll
    for (int rg = 0; rg < 2; ++rg) {
      float tmax = fmaxf(
          fmaxf(fmaxf(fmaxf(sacc[rg][0][0], sacc[rg][0][1]), fmaxf(sacc[rg][0][2], sacc[rg][0][3])),
                fmaxf(fmaxf(sacc[rg][1][0], sacc[rg][1][1]), fmaxf(sacc[rg][1][2], sacc[rg][1][3]))),
          fmaxf(fmaxf(fmaxf(sacc[rg][2][0], sacc[rg][2][1]), fmaxf(sacc[rg][2][2], sacc[rg][2][3])),
                fmaxf(fmaxf(sacc[rg][3][0], sacc[rg][3][1]), fmaxf(sacc[rg][3][2], sacc[rg][3][3]))));
      if (!__all(tmax <= m_s[rg] + RESCALE_THR)) {
        float t2 = fmaxf(tmax, __shfl_xor(tmax, 16));
        t2 = fmaxf(t2, __shfl_xor(t2, 32));          // row-true max over hi-replicas
        float mn = fmaxf(m_s[rg], t2);
        float alpha = exp2f((m_s[rg] - mn) * LOG2E);
        m_s[rg] = mn;
        l_s[rg] *= alpha;
#pragma unroll
        for (int v = 0; v < 4; ++v)
#pragma unroll
          for (int u = 0; u < 4; ++u) zacc[rg][v][u] *= alpha;
      }
      const float ml = m_s[rg] * LOG2E;
      float psum = 0.f;
#pragma unroll
      for (int c = 0; c < 4; ++c)
#pragma unroll
        for (int u = 0; u < 4; ++u) {
          float p = exp2f(sacc[rg][c][u] * LOG2E - ml);
          sacc[rg][c][u] = p;
          psum += p;
        }
      l_s[rg] += psum;  // per-lane partial (this hi-replica's 16 cols)

      char* Pw = (char*)&P[w][rg][0];
#pragma unroll
      for (int c = 0; c < 4; ++c) {
        half4v p4;
#pragma unroll
        for (int u = 0; u < 4; ++u) p4[u] = (_Float16)sacc[rg][c][u];
        int byteoff = (lo << 7) + ((c * 32 + hi * 8) ^ ((lo & 7) << 4));
        *reinterpret_cast<half4v*>(Pw + byteoff) = p4;
      }
    }

    // ---- Z^T += mfma(V, P): V-fragments hoisted across rg ----
#pragma unroll
    for (int s = 0; s < 2; ++s) {
      half8 bV[4];
#pragma unroll
      for (int v = 0; v < 4; ++v) {
        int row = v * 16 + lo;
        bV[v] = *reinterpret_cast<const half8*>(
            Vb + (row << 7) + ((s * 64 + hi * 16) ^ ((row & 7) << 4)));
      }
      int pbyte = (lo << 7) + ((hi * 16 + s * 64) ^ ((lo & 7) << 4));
#pragma unroll
      for (int rg = 0; rg < 2; ++rg) {
        half8 pf = *reinterpret_cast<const half8*>((const char*)&P[w][rg][0] + pbyte);
        __builtin_amdgcn_s_setprio(1);
#pragma unroll
        for (int v = 0; v < 4; ++v)
          zacc[rg][v] = __builtin_amdgcn_mfma_f32_16x16x32_f16(bV[v], pf, zacc[rg][v], 0, 0, 0);
        __builtin_amdgcn_s_setprio(0);
      }
    }
    __syncthreads();  // drains vmcnt(0): next buffer staged & all reads done
    buf ^= 1;
  }

  // finalize: reduce per-lane partial l across hi-replicas, packed 8B stores
  const int b = bh >> 4, h = bh & 15;
#pragma unroll
  for (int rg = 0; rg < 2; ++rg) {
    float l = l_s[rg];
    l += __shfl_xor(l, 16);
    l += __shfl_xor(l, 32);
    const float rl = 1.0f / l;
    const int qrow = qr0 + rg * 16 + lo;
#pragma unroll
    for (int v = 0; v < 4; ++v) {
      half4v o;
#pragma unroll
      for (int u = 0; u < 4; ++u) o[u] = (_Float16)(zacc[rg][v][u] * rl);
      *reinterpret_cast<half4v*>(
          z + ((size_t)b * 1024 + qrow) * 1024 + h * 64 + v * 16 + hi * 4) = o;
    }
  }
}

// ---------------- launch ----------------
extern "C" void kernel_launch(void* const* d_in, const int* in_sizes, int n_in,
                              void* d_out, int out_size, void* d_ws, size_t ws_size,
                              hipStream_t stream) {
  const float* x      = (const float*)d_in[0];
  const float* qkv_w  = (const float*)d_in[1];
  const float* qkv_b  = (const float*)d_in[2];
  const float* proj_w = (const float*)d_in[3];
  const float* proj_b = (const float*)d_in[4];
  float* out = (float*)d_out;

  _Float16* ws    = (_Float16*)d_ws;
  _Float16* xb    = ws;                 // 8388608
  _Float16* wqkv  = ws + 8388608;       // 3145728
  _Float16* wproj = ws + 11534336;      // 1048576
  _Float16* qb    = ws + 12582912;      // 8388608  [BH][1024][64]
  _Float16* kbb   = ws + 20971520;      // 8388608  [BH][1024][64]
  _Float16* vtb   = ws + 29360128;      // 8388608  [BH][64][1024]
  _Float16* zb    = ws + 37748736;      // 8388608  [8192][1024]

  cvt_f32_f16<<<8192, 256, 0, stream>>>(x, xb);
  cvt_f32_f16<<<3072, 256, 0, stream>>>(qkv_w, wqkv);
  cvt_f32_f16<<<1024, 256, 0, stream>>>(proj_w, wproj);

  gemm128<1><<<dim3(64, 24), 256, 0, stream>>>(xb, wqkv, qkv_b, nullptr,
                                               qb, kbb, vtb, 1024, 3072);
  attn_kernel<<<dim3(8, 128), 256, 0, stream>>>(qb, kbb, vtb, zb);
  gemm128<0><<<dim3(64, 8), 256, 0, stream>>>(zb, wproj, proj_b, out,
                                              nullptr, nullptr, nullptr, 1024, 1024);
}

// Round 6
// 262.154 us; speedup vs baseline: 1.0140x; 1.0140x over previous
//
#include <hip/hip_runtime.h>
#include <hip/hip_fp16.h>

// ---------------- types ----------------
typedef _Float16 half8 __attribute__((ext_vector_type(8)));
typedef _Float16 half4v __attribute__((ext_vector_type(4)));
typedef float f32x4 __attribute__((ext_vector_type(4)));

#define GAS1(p) ((const __attribute__((address_space(1))) void*)(p))
#define LAS3(p) ((__attribute__((address_space(3))) void*)(p))

// Problem constants: B=8, N=1024, C=1024, H=16, D_HEAD=64, BH=128, M=8192
#define SCALE 0.125f
#define LOG2E 1.44269504088896340736f
#define RESCALE_THR 8.0f

// ---------------- fused f32 -> f16 conversion (one launch) ----------------
// blocks 0..8191 -> x (8.39M), 8192..11263 -> qkv_w (3.15M), 11264..12287 -> proj_w
__global__ void cvt_all(const float* __restrict__ x, const float* __restrict__ qw,
                        const float* __restrict__ pw, _Float16* __restrict__ xb,
                        _Float16* __restrict__ wqkv, _Float16* __restrict__ wproj) {
  const int b = blockIdx.x;
  const float* src;
  _Float16* dst;
  int j;
  if (b < 8192)       { src = x;  dst = xb;    j = b * 256 + threadIdx.x; }
  else if (b < 11264) { src = qw; dst = wqkv;  j = (b - 8192) * 256 + threadIdx.x; }
  else                { src = pw; dst = wproj; j = (b - 11264) * 256 + threadIdx.x; }
  float4 f = reinterpret_cast<const float4*>(src)[j];
  half4v h;
  h[0] = (_Float16)f.x; h[1] = (_Float16)f.y;
  h[2] = (_Float16)f.z; h[3] = (_Float16)f.w;
  reinterpret_cast<half4v*>(dst)[j] = h;
}

// ---------------- 256x256 8-phase GEMM, BK=64, C = A @ Bw^T (+bias) --------
// T2+T3+T4+T5 stack (guide m201 regime): 8 waves (2Mx4N), 128KB LDS dbuf,
// counted vmcnt (never 0 in steady state), setprio around MFMA clusters,
// rule-21 XOR swizzle (linear LDS dest, inverse-swizzled source, swizzled
// ds_read).  Per K-tile: 3 phase-blocks; stages: A(t+1) in ph1/ph2 (other
// slot, consumed at t-1), B(t+2) in ph3 (same slot, B-halves dead after ph2).
// Boundary vmcnt(4) = the 4 B(t+2) loads may remain outstanding.
// EPI=0: Cf = acc + bias (fp32).  EPI=1: qkv scatter (q*SCALE, k, v^T).
template<int EPI>
__launch_bounds__(512, 1)
__global__ void gemm256(const _Float16* __restrict__ A, const _Float16* __restrict__ Bw,
                        const float* __restrict__ bias, float* __restrict__ Cf,
                        _Float16* __restrict__ qo, _Float16* __restrict__ ko,
                        _Float16* __restrict__ vto, int Kdim, int Ndim) {
  __shared__ alignas(128) _Float16 lds[2][2][2][128 * 64];  // [slot][A/B][half] = 128 KB
  const int tid = threadIdx.x;
  const int w = tid >> 6, lane = tid & 63, lo = lane & 15, hi = lane >> 4;
  const int wm = w >> 2, wn = w & 3;  // 2 x 4 wave grid
  const int tm0 = blockIdx.x * 256, tn0 = blockIdx.y * 256;
  const int T = Kdim >> 6;

  // stage one 128x64 half-tile (op: 0=A,1=B) of K-tile t; 2 x gload_lds x16B.
  auto stage = [&](int op, int t, int half) {
    const _Float16* src = (op ? Bw + (size_t)(tn0 + half * 128) * Kdim
                              : A + (size_t)(tm0 + half * 128) * Kdim) + t * 64;
    char* dst = (char*)&lds[t & 1][op][half][0] + w * 1024;
#pragma unroll
    for (int qq = 0; qq < 2; ++qq) {
      int o = qq * 8192 + w * 1024 + lane * 16;
      int row = o >> 7;
      int kk = ((o & 127) ^ ((row & 7) << 4)) >> 1;
      __builtin_amdgcn_global_load_lds(GAS1(src + (size_t)row * Kdim + kk),
                                       LAS3(dst + qq * 8192), 16, 0, 0);
    }
  };

  f32x4 acc[8][4] = {};

  // prologue: tile0 A+B, tile1 B; one-time vmcnt(0) drain.
  stage(0, 0, 0); stage(0, 0, 1); stage(1, 0, 0); stage(1, 0, 1);
  stage(1, 1, 0); stage(1, 1, 1);
  asm volatile("s_waitcnt vmcnt(0)" ::: "memory");
  __builtin_amdgcn_sched_barrier(0);
  __builtin_amdgcn_s_barrier();
  __builtin_amdgcn_sched_barrier(0);

  for (int t = 0; t < T; ++t) {
    const char* Ab = (const char*)&lds[t & 1][0][wm][0];
    const char* Bb = (const char*)&lds[t & 1][1][wn >> 1][0];
    const int nrow0 = (wn & 1) * 64;
    half8 af[4][2], bf[4][2];

    // ---- phase 1: read A m0..3 + B n0..1 (12 b128); stage A-half0(t+1) ----
#pragma unroll
    for (int m = 0; m < 4; ++m) {
      int row = m * 16 + lo;
#pragma unroll
      for (int s = 0; s < 2; ++s)
        af[m][s] = *reinterpret_cast<const half8*>(
            Ab + (row << 7) + ((s * 64 + hi * 16) ^ ((row & 7) << 4)));
    }
#pragma unroll
    for (int n = 0; n < 2; ++n) {
      int row = nrow0 + n * 16 + lo;
#pragma unroll
      for (int s = 0; s < 2; ++s)
        bf[n][s] = *reinterpret_cast<const half8*>(
            Bb + (row << 7) + ((s * 64 + hi * 16) ^ ((row & 7) << 4)));
    }
    if (t + 1 < T) stage(0, t + 1, 0);
    __builtin_amdgcn_sched_barrier(0);
    __builtin_amdgcn_s_barrier();
    __builtin_amdgcn_sched_barrier(0);
    __builtin_amdgcn_s_setprio(1);
#pragma unroll
    for (int m = 0; m < 4; ++m)
#pragma unroll
      for (int n = 0; n < 2; ++n)
#pragma unroll
        for (int s = 0; s < 2; ++s)
          acc[m][n] = __builtin_amdgcn_mfma_f32_16x16x32_f16(af[m][s], bf[n][s], acc[m][n], 0, 0, 0);
    __builtin_amdgcn_s_setprio(0);

    // ---- phase 2: read B n2..3 (4 b128); stage A-half1(t+1) ----
#pragma unroll
    for (int n = 2; n < 4; ++n) {
      int row = nrow0 + n * 16 + lo;
#pragma unroll
      for (int s = 0; s < 2; ++s)
        bf[n][s] = *reinterpret_cast<const half8*>(
            Bb + (row << 7) + ((s * 64 + hi * 16) ^ ((row & 7) << 4)));
    }
    if (t + 1 < T) stage(0, t + 1, 1);
    __builtin_amdgcn_sched_barrier(0);
    __builtin_amdgcn_s_barrier();
    __builtin_amdgcn_sched_barrier(0);
    __builtin_amdgcn_s_setprio(1);
#pragma unroll
    for (int m = 0; m < 4; ++m)
#pragma unroll
      for (int n = 2; n < 4; ++n)
#pragma unroll
        for (int s = 0; s < 2; ++s)
          acc[m][n] = __builtin_amdgcn_mfma_f32_16x16x32_f16(af[m][s], bf[n][s], acc[m][n], 0, 0, 0);
    __builtin_amdgcn_s_setprio(0);

    // ---- phase 3+4: read A m4..7 (8 b128); stage B0,B1(t+2); 32 MFMA ----
#pragma unroll
    for (int m = 0; m < 4; ++m) {
      int row = 64 + m * 16 + lo;
#pragma unroll
      for (int s = 0; s < 2; ++s)
        af[m][s] = *reinterpret_cast<const half8*>(
            Ab + (row << 7) + ((s * 64 + hi * 16) ^ ((row & 7) << 4)));
    }
    if (t + 2 < T) { stage(1, t + 2, 0); stage(1, t + 2, 1); }
    __builtin_amdgcn_sched_barrier(0);
    __builtin_amdgcn_s_barrier();
    __builtin_amdgcn_sched_barrier(0);
    __builtin_amdgcn_s_setprio(1);
#pragma unroll
    for (int m = 0; m < 4; ++m)
#pragma unroll
      for (int n = 0; n < 4; ++n)
#pragma unroll
        for (int s = 0; s < 2; ++s)
          acc[4 + m][n] = __builtin_amdgcn_mfma_f32_16x16x32_f16(af[m][s], bf[n][s], acc[4 + m][n], 0, 0, 0);
    __builtin_amdgcn_s_setprio(0);

    // ---- tile boundary: counted vmcnt (A(t+1) landed; B(t+2) may fly) ----
    if (t + 1 < T) {
      if (t + 2 < T) asm volatile("s_waitcnt vmcnt(4)" ::: "memory");
      else           asm volatile("s_waitcnt vmcnt(0)" ::: "memory");
      __builtin_amdgcn_sched_barrier(0);
      __builtin_amdgcn_s_barrier();
      __builtin_amdgcn_sched_barrier(0);
    }
  }

  // ---- epilogue.  D row = hi*4+u (A side), col = lo (B side) ----
  if (EPI == 0) {
#pragma unroll
    for (int M = 0; M < 8; ++M) {
      const int gm = tm0 + wm * 128 + M * 16 + hi * 4;
#pragma unroll
      for (int n = 0; n < 4; ++n) {
        const int gc = tn0 + wn * 64 + n * 16 + lo;
        const float bj = bias[gc];
#pragma unroll
        for (int u = 0; u < 4; ++u)
          Cf[(size_t)(gm + u) * Ndim + gc] = acc[M][n][u] + bj;
      }
    }
  } else {
    const int tsel = tn0 >> 10;  // block-uniform: 1024 % 256 == 0
#pragma unroll
    for (int M = 0; M < 8; ++M) {
      const int gm = tm0 + wm * 128 + M * 16 + hi * 4;
      const int b = gm >> 10;
      const int nr = gm & 1023;
#pragma unroll
      for (int n = 0; n < 4; ++n) {
        const int gc = tn0 + wn * 64 + n * 16 + lo;
        const float bj = bias[gc];
        const int h = (gc >> 6) & 15;
        const int d = gc & 63;
        const size_t hb = ((size_t)(b * 16 + h)) << 16;  // *65536
        if (tsel == 0) {
#pragma unroll
          for (int u = 0; u < 4; ++u)
            qo[hb + (size_t)(nr + u) * 64 + d] = (_Float16)((acc[M][n][u] + bj) * SCALE);
        } else if (tsel == 1) {
#pragma unroll
          for (int u = 0; u < 4; ++u)
            ko[hb + (size_t)(nr + u) * 64 + d] = (_Float16)(acc[M][n][u] + bj);
        } else {
          half4v v4;
#pragma unroll
          for (int u = 0; u < 4; ++u) v4[u] = (_Float16)(acc[M][n][u] + bj);
          // V transposed: vt[bh][d][n]; nr % 4 == 0 -> 8B aligned
          *reinterpret_cast<half4v*>(vto + hb + (size_t)d * 1024 + nr) = v4;
        }
      }
    }
  }
}

// ---------------- flash attention (R4 measured-best: 79.5 us) ----------------
// q,k: [BH][1024][64] f16 (q pre-scaled).  vt: [BH][64][1024] f16.
// z out: [B][1024][C] f16.  Grid dim3(8,128).  Swapped-operand S^T/Z^T,
// per-lane softmax, defer-max (T13), LDS 40KB -> 4 blocks/CU.
__launch_bounds__(256, 4)
__global__ void attn_kernel(const _Float16* __restrict__ q, const _Float16* __restrict__ kb,
                            const _Float16* __restrict__ vt, _Float16* __restrict__ z) {
  __shared__ alignas(128) _Float16 Ks[2][64 * 64];  // 16 KB
  __shared__ alignas(128) _Float16 Vs[2][64 * 64];  // 16 KB  (rows = d, cols = n)
  __shared__ alignas(128) _Float16 P[4][16 * 64];   // 8 KB, per-wave swizzled
  const int tid = threadIdx.x;
  const int w = tid >> 6, lane = tid & 63, lo = lane & 15, hi = lane >> 4;
  const int bh = blockIdx.y;
  const int qr0 = blockIdx.x * 128 + w * 32;
  const size_t base = (size_t)bh << 16;  // *65536

  auto stage = [&](int buf, int kt) {
#pragma unroll
    for (int p = 0; p < 2; ++p) {
      int o = p * 4096 + w * 1024 + lane * 16;
      int row = o >> 7;
      int kk = ((o & 127) ^ ((row & 7) << 4)) >> 1;
      __builtin_amdgcn_global_load_lds(GAS1(kb + base + (size_t)(kt + row) * 64 + kk),
                                       LAS3((char*)&Ks[buf][0] + p * 4096 + w * 1024), 16, 0, 0);
      __builtin_amdgcn_global_load_lds(GAS1(vt + base + (size_t)row * 1024 + kt + kk),
                                       LAS3((char*)&Vs[buf][0] + p * 4096 + w * 1024), 16, 0, 0);
    }
  };

  stage(0, 0);

  half8 qf[2][2];  // B-fragment: lane lo = q-row qr0+rg*16+lo, k-slice s*32+hi*8
#pragma unroll
  for (int rg = 0; rg < 2; ++rg)
#pragma unroll
    for (int s = 0; s < 2; ++s)
      qf[rg][s] = *reinterpret_cast<const half8*>(
          q + base + (size_t)(qr0 + rg * 16 + lo) * 64 + s * 32 + hi * 8);

  f32x4 zacc[2][4] = {};        // Z^T: zacc[rg][v][u] = Z[q=lo][d=16v+4hi+u]
  float m_s[2] = {-1e30f, -1e30f};
  float l_s[2] = {0.f, 0.f};

  char* Pw = (char*)&P[w][0];
  __syncthreads();

  int buf = 0;
  for (int kt = 0; kt < 1024; kt += 64) {
    if (kt + 64 < 1024) stage(buf ^ 1, kt + 64);
    const char* Kb = (const char*)&Ks[buf][0];
    const char* Vb = (const char*)&Vs[buf][0];

    // ---- S^T = mfma(K, Q): sacc[rg][c][u] = S[q=lo][k=16c+4hi+u] ----
    f32x4 sacc[2][4];
#pragma unroll
    for (int rg = 0; rg < 2; ++rg)
#pragma unroll
      for (int c = 0; c < 4; ++c) sacc[rg][c] = f32x4{0.f, 0.f, 0.f, 0.f};
#pragma unroll
    for (int c = 0; c < 4; ++c) {
      const int row = c * 16 + lo;
      half8 bK0 = *reinterpret_cast<const half8*>(
          Kb + (row << 7) + ((hi * 16) ^ ((row & 7) << 4)));
      half8 bK1 = *reinterpret_cast<const half8*>(
          Kb + (row << 7) + ((64 + hi * 16) ^ ((row & 7) << 4)));
      __builtin_amdgcn_s_setprio(1);
#pragma unroll
      for (int rg = 0; rg < 2; ++rg) {
        sacc[rg][c] = __builtin_amdgcn_mfma_f32_16x16x32_f16(bK0, qf[rg][0], sacc[rg][c], 0, 0, 0);
        sacc[rg][c] = __builtin_amdgcn_mfma_f32_16x16x32_f16(bK1, qf[rg][1], sacc[rg][c], 0, 0, 0);
      }
      __builtin_amdgcn_s_setprio(0);
    }

#pragma unroll
    for (int rg = 0; rg < 2; ++rg) {
      // ---- per-lane online softmax (q-row = lo), defer-max ----
      float tmax = fmaxf(
          fmaxf(fmaxf(fmaxf(sacc[rg][0][0], sacc[rg][0][1]), fmaxf(sacc[rg][0][2], sacc[rg][0][3])),
                fmaxf(fmaxf(sacc[rg][1][0], sacc[rg][1][1]), fmaxf(sacc[rg][1][2], sacc[rg][1][3]))),
          fmaxf(fmaxf(fmaxf(sacc[rg][2][0], sacc[rg][2][1]), fmaxf(sacc[rg][2][2], sacc[rg][2][3])),
                fmaxf(fmaxf(sacc[rg][3][0], sacc[rg][3][1]), fmaxf(sacc[rg][3][2], sacc[rg][3][3]))));
      if (!__all(tmax <= m_s[rg] + RESCALE_THR)) {
        float t2 = fmaxf(tmax, __shfl_xor(tmax, 16));
        t2 = fmaxf(t2, __shfl_xor(t2, 32));          // row-true max over hi-replicas
        float mn = fmaxf(m_s[rg], t2);
        float alpha = exp2f((m_s[rg] - mn) * LOG2E);
        m_s[rg] = mn;
        l_s[rg] *= alpha;
#pragma unroll
        for (int v = 0; v < 4; ++v)
#pragma unroll
          for (int u = 0; u < 4; ++u) zacc[rg][v][u] *= alpha;
      }
      const float ml = m_s[rg] * LOG2E;
      float psum = 0.f;
#pragma unroll
      for (int c = 0; c < 4; ++c)
#pragma unroll
        for (int u = 0; u < 4; ++u) {
          float p = exp2f(sacc[rg][c][u] * LOG2E - ml);
          sacc[rg][c][u] = p;
          psum += p;
        }
      l_s[rg] += psum;  // per-lane partial (this hi-replica's 16 cols)

      // ---- packed P write: P[q=lo][k=16c+4hi+u], 4x ds_write_b64 ----
#pragma unroll
      for (int c = 0; c < 4; ++c) {
        half4v p4;
#pragma unroll
        for (int u = 0; u < 4; ++u) p4[u] = (_Float16)sacc[rg][c][u];
        int byteoff = (lo << 7) + ((c * 32 + hi * 8) ^ ((lo & 7) << 4));
        *reinterpret_cast<half4v*>(Pw + byteoff) = p4;
      }

      // ---- Z^T += mfma(V, P) ----
#pragma unroll
      for (int s = 0; s < 2; ++s) {
        int pbyte = (lo << 7) + ((hi * 16 + s * 64) ^ ((lo & 7) << 4));
        half8 pf = *reinterpret_cast<const half8*>((const char*)Pw + pbyte);
        half8 bV[4];
#pragma unroll
        for (int v = 0; v < 4; ++v) {
          int row = v * 16 + lo;
          bV[v] = *reinterpret_cast<const half8*>(
              Vb + (row << 7) + ((s * 64 + hi * 16) ^ ((row & 7) << 4)));
        }
        __builtin_amdgcn_s_setprio(1);
#pragma unroll
        for (int v = 0; v < 4; ++v)
          zacc[rg][v] = __builtin_amdgcn_mfma_f32_16x16x32_f16(bV[v], pf, zacc[rg][v], 0, 0, 0);
        __builtin_amdgcn_s_setprio(0);
      }
    }
    __syncthreads();  // drains vmcnt(0): next buffer staged & all reads done
    buf ^= 1;
  }

  // finalize: reduce per-lane partial l across hi-replicas, packed 8B stores
  const int b = bh >> 4, h = bh & 15;
#pragma unroll
  for (int rg = 0; rg < 2; ++rg) {
    float l = l_s[rg];
    l += __shfl_xor(l, 16);
    l += __shfl_xor(l, 32);
    const float rl = 1.0f / l;
    const int qrow = qr0 + rg * 16 + lo;
#pragma unroll
    for (int v = 0; v < 4; ++v) {
      half4v o;
#pragma unroll
      for (int u = 0; u < 4; ++u) o[u] = (_Float16)(zacc[rg][v][u] * rl);
      *reinterpret_cast<half4v*>(
          z + ((size_t)b * 1024 + qrow) * 1024 + h * 64 + v * 16 + hi * 4) = o;
    }
  }
}

// ---------------- launch ----------------
extern "C" void kernel_launch(void* const* d_in, const int* in_sizes, int n_in,
                              void* d_out, int out_size, void* d_ws, size_t ws_size,
                              hipStream_t stream) {
  const float* x      = (const float*)d_in[0];
  const float* qkv_w  = (const float*)d_in[1];
  const float* qkv_b  = (const float*)d_in[2];
  const float* proj_w = (const float*)d_in[3];
  const float* proj_b = (const float*)d_in[4];
  float* out = (float*)d_out;

  _Float16* ws    = (_Float16*)d_ws;
  _Float16* xb    = ws;                 // 8388608
  _Float16* wqkv  = ws + 8388608;       // 3145728
  _Float16* wproj = ws + 11534336;      // 1048576
  _Float16* qb    = ws + 12582912;      // 8388608  [BH][1024][64]
  _Float16* kbb   = ws + 20971520;      // 8388608  [BH][1024][64]
  _Float16* vtb   = ws + 29360128;      // 8388608  [BH][64][1024]
  _Float16* zb    = ws + 37748736;      // 8388608  [8192][1024]

  cvt_all<<<12288, 256, 0, stream>>>(x, qkv_w, proj_w, xb, wqkv, wproj);

  gemm256<1><<<dim3(32, 12), 512, 0, stream>>>(xb, wqkv, qkv_b, nullptr,
                                               qb, kbb, vtb, 1024, 3072);
  attn_kernel<<<dim3(8, 128), 256, 0, stream>>>(qb, kbb, vtb, zb);
  gemm256<0><<<dim3(32, 4), 512, 0, stream>>>(zb, wproj, proj_b, out,
                                              nullptr, nullptr, nullptr, 1024, 1024);
}

// Round 8
// 254.956 us; speedup vs baseline: 1.0426x; 1.0282x over previous
//
#include <hip/hip_runtime.h>
#include <hip/hip_fp16.h>

// ---------------- types ----------------
typedef _Float16 half8 __attribute__((ext_vector_type(8)));
typedef _Float16 half4v __attribute__((ext_vector_type(4)));
typedef float f32x4 __attribute__((ext_vector_type(4)));

#define GAS1(p) ((const __attribute__((address_space(1))) void*)(p))
#define LAS3(p) ((__attribute__((address_space(3))) void*)(p))

// Problem constants: B=8, N=1024, C=1024, H=16, D_HEAD=64, BH=128, M=8192
#define SCALE 0.125f
#define LOG2E 1.44269504088896340736f
#define RESCALE_THR 8.0f

// ---------------- fused f32 -> f16 conversion (one launch) ----------------
__global__ void cvt_all(const float* __restrict__ x, const float* __restrict__ qw,
                        const float* __restrict__ pw, _Float16* __restrict__ xb,
                        _Float16* __restrict__ wqkv, _Float16* __restrict__ wproj) {
  const int b = blockIdx.x;
  const float* src;
  _Float16* dst;
  int j;
  if (b < 8192)       { src = x;  dst = xb;    j = b * 256 + threadIdx.x; }
  else if (b < 11264) { src = qw; dst = wqkv;  j = (b - 8192) * 256 + threadIdx.x; }
  else                { src = pw; dst = wproj; j = (b - 11264) * 256 + threadIdx.x; }
  float4 f = reinterpret_cast<const float4*>(src)[j];
  half4v h;
  h[0] = (_Float16)f.x; h[1] = (_Float16)f.y;
  h[2] = (_Float16)f.z; h[3] = (_Float16)f.w;
  reinterpret_cast<half4v*>(dst)[j] = h;
}

// ---------------- 256x256 8-phase GEMM (QKV), BK=64 ----------------
// T2+T3+T4+T5 stack; counted vmcnt; rule-21 swizzle.  EPI=1 qkv scatter.
template<int EPI>
__launch_bounds__(512, 1)
__global__ void gemm256(const _Float16* __restrict__ A, const _Float16* __restrict__ Bw,
                        const float* __restrict__ bias, float* __restrict__ Cf,
                        _Float16* __restrict__ qo, _Float16* __restrict__ ko,
                        _Float16* __restrict__ vto, int Kdim, int Ndim) {
  __shared__ alignas(128) _Float16 lds[2][2][2][128 * 64];  // 128 KB
  const int tid = threadIdx.x;
  const int w = tid >> 6, lane = tid & 63, lo = lane & 15, hi = lane >> 4;
  const int wm = w >> 2, wn = w & 3;
  const int tm0 = blockIdx.x * 256, tn0 = blockIdx.y * 256;
  const int T = Kdim >> 6;

  auto stage = [&](int op, int t, int half) {
    const _Float16* src = (op ? Bw + (size_t)(tn0 + half * 128) * Kdim
                              : A + (size_t)(tm0 + half * 128) * Kdim) + t * 64;
    char* dst = (char*)&lds[t & 1][op][half][0] + w * 1024;
#pragma unroll
    for (int qq = 0; qq < 2; ++qq) {
      int o = qq * 8192 + w * 1024 + lane * 16;
      int row = o >> 7;
      int kk = ((o & 127) ^ ((row & 7) << 4)) >> 1;
      __builtin_amdgcn_global_load_lds(GAS1(src + (size_t)row * Kdim + kk),
                                       LAS3(dst + qq * 8192), 16, 0, 0);
    }
  };

  f32x4 acc[8][4] = {};

  stage(0, 0, 0); stage(0, 0, 1); stage(1, 0, 0); stage(1, 0, 1);
  stage(1, 1, 0); stage(1, 1, 1);
  asm volatile("s_waitcnt vmcnt(0)" ::: "memory");
  __builtin_amdgcn_sched_barrier(0);
  __builtin_amdgcn_s_barrier();
  __builtin_amdgcn_sched_barrier(0);

  for (int t = 0; t < T; ++t) {
    const char* Ab = (const char*)&lds[t & 1][0][wm][0];
    const char* Bb = (const char*)&lds[t & 1][1][wn >> 1][0];
    const int nrow0 = (wn & 1) * 64;
    half8 af[4][2], bf[4][2];

    // ---- phase 1: read A m0..3 + B n0..1; stage A-half0(t+1) ----
#pragma unroll
    for (int m = 0; m < 4; ++m) {
      int row = m * 16 + lo;
#pragma unroll
      for (int s = 0; s < 2; ++s)
        af[m][s] = *reinterpret_cast<const half8*>(
            Ab + (row << 7) + ((s * 64 + hi * 16) ^ ((row & 7) << 4)));
    }
#pragma unroll
    for (int n = 0; n < 2; ++n) {
      int row = nrow0 + n * 16 + lo;
#pragma unroll
      for (int s = 0; s < 2; ++s)
        bf[n][s] = *reinterpret_cast<const half8*>(
            Bb + (row << 7) + ((s * 64 + hi * 16) ^ ((row & 7) << 4)));
    }
    if (t + 1 < T) stage(0, t + 1, 0);
    __builtin_amdgcn_sched_barrier(0);
    __builtin_amdgcn_s_barrier();
    __builtin_amdgcn_sched_barrier(0);
    __builtin_amdgcn_s_setprio(1);
#pragma unroll
    for (int m = 0; m < 4; ++m)
#pragma unroll
      for (int n = 0; n < 2; ++n)
#pragma unroll
        for (int s = 0; s < 2; ++s)
          acc[m][n] = __builtin_amdgcn_mfma_f32_16x16x32_f16(af[m][s], bf[n][s], acc[m][n], 0, 0, 0);
    __builtin_amdgcn_s_setprio(0);

    // ---- phase 2: read B n2..3; stage A-half1(t+1) ----
#pragma unroll
    for (int n = 2; n < 4; ++n) {
      int row = nrow0 + n * 16 + lo;
#pragma unroll
      for (int s = 0; s < 2; ++s)
        bf[n][s] = *reinterpret_cast<const half8*>(
            Bb + (row << 7) + ((s * 64 + hi * 16) ^ ((row & 7) << 4)));
    }
    if (t + 1 < T) stage(0, t + 1, 1);
    __builtin_amdgcn_sched_barrier(0);
    __builtin_amdgcn_s_barrier();
    __builtin_amdgcn_sched_barrier(0);
    __builtin_amdgcn_s_setprio(1);
#pragma unroll
    for (int m = 0; m < 4; ++m)
#pragma unroll
      for (int n = 2; n < 4; ++n)
#pragma unroll
        for (int s = 0; s < 2; ++s)
          acc[m][n] = __builtin_amdgcn_mfma_f32_16x16x32_f16(af[m][s], bf[n][s], acc[m][n], 0, 0, 0);
    __builtin_amdgcn_s_setprio(0);

    // ---- phase 3: read A m4..7; stage B(t+2); 32 MFMA ----
#pragma unroll
    for (int m = 0; m < 4; ++m) {
      int row = 64 + m * 16 + lo;
#pragma unroll
      for (int s = 0; s < 2; ++s)
        af[m][s] = *reinterpret_cast<const half8*>(
            Ab + (row << 7) + ((s * 64 + hi * 16) ^ ((row & 7) << 4)));
    }
    if (t + 2 < T) { stage(1, t + 2, 0); stage(1, t + 2, 1); }
    __builtin_amdgcn_sched_barrier(0);
    __builtin_amdgcn_s_barrier();
    __builtin_amdgcn_sched_barrier(0);
    __builtin_amdgcn_s_setprio(1);
#pragma unroll
    for (int m = 0; m < 4; ++m)
#pragma unroll
      for (int n = 0; n < 4; ++n)
#pragma unroll
        for (int s = 0; s < 2; ++s)
          acc[4 + m][n] = __builtin_amdgcn_mfma_f32_16x16x32_f16(af[m][s], bf[n][s], acc[4 + m][n], 0, 0, 0);
    __builtin_amdgcn_s_setprio(0);

    if (t + 1 < T) {
      if (t + 2 < T) asm volatile("s_waitcnt vmcnt(4)" ::: "memory");
      else           asm volatile("s_waitcnt vmcnt(0)" ::: "memory");
      __builtin_amdgcn_sched_barrier(0);
      __builtin_amdgcn_s_barrier();
      __builtin_amdgcn_sched_barrier(0);
    }
  }

  if (EPI == 0) {
#pragma unroll
    for (int M = 0; M < 8; ++M) {
      const int gm = tm0 + wm * 128 + M * 16 + hi * 4;
#pragma unroll
      for (int n = 0; n < 4; ++n) {
        const int gc = tn0 + wn * 64 + n * 16 + lo;
        const float bj = bias[gc];
#pragma unroll
        for (int u = 0; u < 4; ++u)
          Cf[(size_t)(gm + u) * Ndim + gc] = acc[M][n][u] + bj;
      }
    }
  } else {
    const int tsel = tn0 >> 10;
#pragma unroll
    for (int M = 0; M < 8; ++M) {
      const int gm = tm0 + wm * 128 + M * 16 + hi * 4;
      const int b = gm >> 10;
      const int nr = gm & 1023;
#pragma unroll
      for (int n = 0; n < 4; ++n) {
        const int gc = tn0 + wn * 64 + n * 16 + lo;
        const float bj = bias[gc];
        const int h = (gc >> 6) & 15;
        const int d = gc & 63;
        const size_t hb = ((size_t)(b * 16 + h)) << 16;
        if (tsel == 0) {
#pragma unroll
          for (int u = 0; u < 4; ++u)
            qo[hb + (size_t)(nr + u) * 64 + d] = (_Float16)((acc[M][n][u] + bj) * SCALE);
        } else if (tsel == 1) {
#pragma unroll
          for (int u = 0; u < 4; ++u)
            ko[hb + (size_t)(nr + u) * 64 + d] = (_Float16)(acc[M][n][u] + bj);
        } else {
          half4v v4;
#pragma unroll
          for (int u = 0; u < 4; ++u) v4[u] = (_Float16)(acc[M][n][u] + bj);
          *reinterpret_cast<half4v*>(vto + hb + (size_t)d * 1024 + nr) = v4;
        }
      }
    }
  }
}

// ---------------- 128x128 GEMM (proj), BK=64, R4-measured config ----------
__launch_bounds__(256, 2)
__global__ void gemm128(const _Float16* __restrict__ A, const _Float16* __restrict__ Bw,
                        const float* __restrict__ bias, float* __restrict__ Cf,
                        int Kdim, int Ndim) {
  __shared__ alignas(128) _Float16 As[128 * 64];
  __shared__ alignas(128) _Float16 Bs[128 * 64];
  const int tid = threadIdx.x;
  const int w = tid >> 6, lane = tid & 63, lo = lane & 15, hi = lane >> 4;
  const int wr = w >> 1, wc = w & 1;
  const int tm0 = blockIdx.x * 128;
  const int tn0 = blockIdx.y * 128;

  f32x4 acc[4][4] = {};

  for (int k0 = 0; k0 < Kdim; k0 += 64) {
    __syncthreads();
#pragma unroll
    for (int r = 0; r < 4; ++r) {
      int o = r * 4096 + w * 1024 + lane * 16;
      int row = o >> 7;
      int kk = ((o & 127) ^ ((row & 7) << 4)) >> 1;
      __builtin_amdgcn_global_load_lds(GAS1(A + (size_t)(tm0 + row) * Kdim + k0 + kk),
                                       LAS3((char*)As + r * 4096 + w * 1024), 16, 0, 0);
      __builtin_amdgcn_global_load_lds(GAS1(Bw + (size_t)(tn0 + row) * Kdim + k0 + kk),
                                       LAS3((char*)Bs + r * 4096 + w * 1024), 16, 0, 0);
    }
    __syncthreads();
#pragma unroll
    for (int s = 0; s < 2; ++s) {
      half8 af[4], bf[4];
#pragma unroll
      for (int i = 0; i < 4; ++i) {
        int arow = wr * 64 + i * 16 + lo;
        int abyte = (arow << 7) + ((hi * 16 + s * 64) ^ ((arow & 7) << 4));
        af[i] = *reinterpret_cast<const half8*>((const char*)As + abyte);
        int brow = wc * 64 + i * 16 + lo;
        int bbyte = (brow << 7) + ((hi * 16 + s * 64) ^ ((brow & 7) << 4));
        bf[i] = *reinterpret_cast<const half8*>((const char*)Bs + bbyte);
      }
#pragma unroll
      for (int i = 0; i < 4; ++i)
#pragma unroll
        for (int j = 0; j < 4; ++j)
          acc[i][j] = __builtin_amdgcn_mfma_f32_16x16x32_f16(af[i], bf[j], acc[i][j], 0, 0, 0);
    }
  }

#pragma unroll
  for (int i = 0; i < 4; ++i) {
    const int m0 = tm0 + wr * 64 + i * 16 + hi * 4;
#pragma unroll
    for (int j = 0; j < 4; ++j) {
      const int n = tn0 + wc * 64 + j * 16 + lo;
      const float bj = bias[n];
#pragma unroll
      for (int r = 0; r < 4; ++r)
        Cf[(size_t)(m0 + r) * Ndim + n] = acc[i][j][r] + bj;
    }
  }
}

// ---------------- flash attention v6 (swapped-operand, l via MFMA) --------
// q,k: [BH][1024][64] f16 (q pre-scaled).  vt: [BH][64][1024] f16.
// z out: [B][1024][C] f16.  Grid dim3(8,128).  R4 structure (measured 79.5us)
// + row-sum l folded into matrix pipe: extra ones-A MFMA per PV step
// accumulates zsum = sum_k P[k][q] (removes 32 VALU adds/tile + end shfls).
__launch_bounds__(256, 4)
__global__ void attn_kernel(const _Float16* __restrict__ q, const _Float16* __restrict__ kb,
                            const _Float16* __restrict__ vt, _Float16* __restrict__ z) {
  __shared__ alignas(128) _Float16 Ks[2][64 * 64];  // 16 KB
  __shared__ alignas(128) _Float16 Vs[2][64 * 64];  // 16 KB  (rows = d, cols = n)
  __shared__ alignas(128) _Float16 P[4][16 * 64];   // 8 KB, per-wave swizzled
  const int tid = threadIdx.x;
  const int w = tid >> 6, lane = tid & 63, lo = lane & 15, hi = lane >> 4;
  const int bh = blockIdx.y;
  const int qr0 = blockIdx.x * 128 + w * 32;
  const size_t base = (size_t)bh << 16;  // *65536

  auto stage = [&](int buf, int kt) {
#pragma unroll
    for (int p = 0; p < 2; ++p) {
      int o = p * 4096 + w * 1024 + lane * 16;
      int row = o >> 7;
      int kk = ((o & 127) ^ ((row & 7) << 4)) >> 1;
      __builtin_amdgcn_global_load_lds(GAS1(kb + base + (size_t)(kt + row) * 64 + kk),
                                       LAS3((char*)&Ks[buf][0] + p * 4096 + w * 1024), 16, 0, 0);
      __builtin_amdgcn_global_load_lds(GAS1(vt + base + (size_t)row * 1024 + kt + kk),
                                       LAS3((char*)&Vs[buf][0] + p * 4096 + w * 1024), 16, 0, 0);
    }
  };

  stage(0, 0);

  half8 qf[2][2];
#pragma unroll
  for (int rg = 0; rg < 2; ++rg)
#pragma unroll
    for (int s = 0; s < 2; ++s)
      qf[rg][s] = *reinterpret_cast<const half8*>(
          q + base + (size_t)(qr0 + rg * 16 + lo) * 64 + s * 32 + hi * 8);

  half8 ones;
#pragma unroll
  for (int j = 0; j < 8; ++j) ones[j] = (_Float16)1.0f;

  f32x4 zacc[2][4] = {};        // Z^T: zacc[rg][v][u] = Z[q=lo][d=16v+4hi+u]
  f32x4 zsum[2] = {};           // zsum[rg][*] = l (all rows equal; col q=lo)
  float m_s[2] = {-1e30f, -1e30f};

  char* Pw = (char*)&P[w][0];
  __syncthreads();

  int buf = 0;
  for (int kt = 0; kt < 1024; kt += 64) {
    if (kt + 64 < 1024) stage(buf ^ 1, kt + 64);
    const char* Kb = (const char*)&Ks[buf][0];
    const char* Vb = (const char*)&Vs[buf][0];

    // ---- S^T = mfma(K, Q): sacc[rg][c][u] = S[q=lo][k=16c+4hi+u] ----
    f32x4 sacc[2][4];
#pragma unroll
    for (int rg = 0; rg < 2; ++rg)
#pragma unroll
      for (int c = 0; c < 4; ++c) sacc[rg][c] = f32x4{0.f, 0.f, 0.f, 0.f};
#pragma unroll
    for (int c = 0; c < 4; ++c) {
      const int row = c * 16 + lo;
      half8 bK0 = *reinterpret_cast<const half8*>(
          Kb + (row << 7) + ((hi * 16) ^ ((row & 7) << 4)));
      half8 bK1 = *reinterpret_cast<const half8*>(
          Kb + (row << 7) + ((64 + hi * 16) ^ ((row & 7) << 4)));
      __builtin_amdgcn_s_setprio(1);
#pragma unroll
      for (int rg = 0; rg < 2; ++rg) {
        sacc[rg][c] = __builtin_amdgcn_mfma_f32_16x16x32_f16(bK0, qf[rg][0], sacc[rg][c], 0, 0, 0);
        sacc[rg][c] = __builtin_amdgcn_mfma_f32_16x16x32_f16(bK1, qf[rg][1], sacc[rg][c], 0, 0, 0);
      }
      __builtin_amdgcn_s_setprio(0);
    }

#pragma unroll
    for (int rg = 0; rg < 2; ++rg) {
      // ---- per-lane online softmax (q-row = lo), defer-max ----
      float tmax = fmaxf(
          fmaxf(fmaxf(fmaxf(sacc[rg][0][0], sacc[rg][0][1]), fmaxf(sacc[rg][0][2], sacc[rg][0][3])),
                fmaxf(fmaxf(sacc[rg][1][0], sacc[rg][1][1]), fmaxf(sacc[rg][1][2], sacc[rg][1][3]))),
          fmaxf(fmaxf(fmaxf(sacc[rg][2][0], sacc[rg][2][1]), fmaxf(sacc[rg][2][2], sacc[rg][2][3])),
                fmaxf(fmaxf(sacc[rg][3][0], sacc[rg][3][1]), fmaxf(sacc[rg][3][2], sacc[rg][3][3]))));
      if (!__all(tmax <= m_s[rg] + RESCALE_THR)) {
        float t2 = fmaxf(tmax, __shfl_xor(tmax, 16));
        t2 = fmaxf(t2, __shfl_xor(t2, 32));
        float mn = fmaxf(m_s[rg], t2);
        float alpha = exp2f((m_s[rg] - mn) * LOG2E);
        m_s[rg] = mn;
#pragma unroll
        for (int u = 0; u < 4; ++u) zsum[rg][u] *= alpha;
#pragma unroll
        for (int v = 0; v < 4; ++v)
#pragma unroll
          for (int u = 0; u < 4; ++u) zacc[rg][v][u] *= alpha;
      }
      const float ml = m_s[rg] * LOG2E;
#pragma unroll
      for (int c = 0; c < 4; ++c)
#pragma unroll
        for (int u = 0; u < 4; ++u)
          sacc[rg][c][u] = exp2f(sacc[rg][c][u] * LOG2E - ml);

      // ---- packed P write: P[q=lo][k=16c+4hi+u], 4x ds_write_b64 ----
#pragma unroll
      for (int c = 0; c < 4; ++c) {
        half4v p4;
#pragma unroll
        for (int u = 0; u < 4; ++u) p4[u] = (_Float16)sacc[rg][c][u];
        int byteoff = (lo << 7) + ((c * 32 + hi * 8) ^ ((lo & 7) << 4));
        *reinterpret_cast<half4v*>(Pw + byteoff) = p4;
      }

      // ---- Z^T += mfma(V, P); l += mfma(ones, P) ----
#pragma unroll
      for (int s = 0; s < 2; ++s) {
        int pbyte = (lo << 7) + ((hi * 16 + s * 64) ^ ((lo & 7) << 4));
        half8 pf = *reinterpret_cast<const half8*>((const char*)Pw + pbyte);
        half8 bV[4];
#pragma unroll
        for (int v = 0; v < 4; ++v) {
          int row = v * 16 + lo;
          bV[v] = *reinterpret_cast<const half8*>(
              Vb + (row << 7) + ((s * 64 + hi * 16) ^ ((row & 7) << 4)));
        }
        __builtin_amdgcn_s_setprio(1);
        zsum[rg] = __builtin_amdgcn_mfma_f32_16x16x32_f16(ones, pf, zsum[rg], 0, 0, 0);
#pragma unroll
        for (int v = 0; v < 4; ++v)
          zacc[rg][v] = __builtin_amdgcn_mfma_f32_16x16x32_f16(bV[v], pf, zacc[rg][v], 0, 0, 0);
        __builtin_amdgcn_s_setprio(0);
      }
    }
    __syncthreads();
    buf ^= 1;
  }

  // finalize: l = zsum[rg][0] (every row of the ones-MFMA equals the colsum)
  const int b = bh >> 4, h = bh & 15;
#pragma unroll
  for (int rg = 0; rg < 2; ++rg) {
    const float rl = 1.0f / zsum[rg][0];
    const int qrow = qr0 + rg * 16 + lo;
#pragma unroll
    for (int v = 0; v < 4; ++v) {
      half4v o;
#pragma unroll
      for (int u = 0; u < 4; ++u) o[u] = (_Float16)(zacc[rg][v][u] * rl);
      *reinterpret_cast<half4v*>(
          z + ((size_t)b * 1024 + qrow) * 1024 + h * 64 + v * 16 + hi * 4) = o;
    }
  }
}

// ---------------- launch ----------------
extern "C" void kernel_launch(void* const* d_in, const int* in_sizes, int n_in,
                              void* d_out, int out_size, void* d_ws, size_t ws_size,
                              hipStream_t stream) {
  const float* x      = (const float*)d_in[0];
  const float* qkv_w  = (const float*)d_in[1];
  const float* qkv_b  = (const float*)d_in[2];
  const float* proj_w = (const float*)d_in[3];
  const float* proj_b = (const float*)d_in[4];
  float* out = (float*)d_out;

  _Float16* ws    = (_Float16*)d_ws;
  _Float16* xb    = ws;                 // 8388608
  _Float16* wqkv  = ws + 8388608;       // 3145728
  _Float16* wproj = ws + 11534336;      // 1048576
  _Float16* qb    = ws + 12582912;      // 8388608  [BH][1024][64]
  _Float16* kbb   = ws + 20971520;      // 8388608  [BH][1024][64]
  _Float16* vtb   = ws + 29360128;      // 8388608  [BH][64][1024]
  _Float16* zb    = ws + 37748736;      // 8388608  [8192][1024]

  cvt_all<<<12288, 256, 0, stream>>>(x, qkv_w, proj_w, xb, wqkv, wproj);

  gemm256<1><<<dim3(32, 12), 512, 0, stream>>>(xb, wqkv, qkv_b, nullptr,
                                               qb, kbb, vtb, 1024, 3072);
  attn_kernel<<<dim3(8, 128), 256, 0, stream>>>(qb, kbb, vtb, zb);
  gemm128<<<dim3(64, 8), 256, 0, stream>>>(zb, wproj, proj_b, out, 1024, 1024);
}